// Round 1
// baseline (1692.054 us; speedup 1.0000x reference)
//
#include <hip/hip_runtime.h>
#include <math.h>

#define NN 100000
#define NE 1600000
#define GIN 128
#define GH 64
#define GOUT 10
#define NG 512
#define TPB 256

__global__ void k_zero(float* __restrict__ p, int n) {
  int i = blockIdx.x * TPB + threadIdx.x;
  if (i < n) p[i] = 0.0f;
}

__global__ void k_deg(const int* __restrict__ col, float* __restrict__ deg) {
  int e = blockIdx.x * TPB + threadIdx.x;
  if (e < NE) unsafeAtomicAdd(&deg[col[e]], 1.0f);
}

__global__ void k_dinv(float* __restrict__ deg) {
  int i = blockIdx.x * TPB + threadIdx.x;
  if (i < NN) deg[i] = rsqrtf(deg[i] + 1.0f);  // +1 = self-loop
}

// Y[n,f] = sum_k X[n,k] * W[k,f]; W staged in LDS; LPR lanes per row.
template<int K, int D, int LPR>
__global__ void k_matmul(const float* __restrict__ X, const float* __restrict__ W,
                         float* __restrict__ Y) {
  __shared__ float Wl[K * D];
  for (int i = threadIdx.x; i < K * D; i += TPB) Wl[i] = W[i];
  __syncthreads();
  const int rpb = TPB / LPR;
  int n = blockIdx.x * rpb + threadIdx.x / LPR;
  int f = threadIdx.x % LPR;
  if (n >= NN || f >= D) return;
  const float* xr = X + (size_t)n * K;
  float acc = 0.0f;
#pragma unroll
  for (int k = 0; k < K; ++k) acc += xr[k] * Wl[k * D + f];
  Y[(size_t)n * D + f] = acc;
}

// out[n,f] = hw[n,f] * dinv[n]^2   (self-loop term doubles as the zero-init)
template<int D, int LPR>
__global__ void k_selfloop(const float* __restrict__ hw, const float* __restrict__ dinv,
                           float* __restrict__ out) {
  int i = blockIdx.x * TPB + threadIdx.x;
  int n = i / LPR, f = i % LPR;
  if (n >= NN || f >= D) return;
  float d = dinv[n];
  out[(size_t)n * D + f] = hw[(size_t)n * D + f] * d * d;
}

// out[col,f] += hw[row,f] * dinv[row]*dinv[col]
template<int D, int LPR>
__global__ void k_agg(const int* __restrict__ row, const int* __restrict__ col,
                      const float* __restrict__ dinv, const float* __restrict__ hw,
                      float* __restrict__ out) {
  int i = blockIdx.x * TPB + threadIdx.x;
  int e = i / LPR, f = i % LPR;
  if (e >= NE || f >= D) return;
  int r = row[e], c = col[e];
  float nrm = dinv[r] * dinv[c];
  unsafeAtomicAdd(&out[(size_t)c * D + f], hw[(size_t)r * D + f] * nrm);
}

template<int D, int LPR, bool RELU>
__global__ void k_bias(float* __restrict__ out, const float* __restrict__ b) {
  int i = blockIdx.x * TPB + threadIdx.x;
  int n = i / LPR, f = i % LPR;
  if (n >= NN || f >= D) return;
  float v = out[(size_t)n * D + f] + b[f];
  if (RELU) v = fmaxf(v, 0.0f);
  out[(size_t)n * D + f] = v;
}

__global__ void k_pool(const float* __restrict__ h, const int* __restrict__ batch,
                       float* __restrict__ s, float* __restrict__ cnt) {
  int i = blockIdx.x * TPB + threadIdx.x;
  int n = i >> 4, f = i & 15;
  if (n >= NN) return;
  int g = batch[n];
  if (f < GOUT) unsafeAtomicAdd(&s[g * GOUT + f], h[(size_t)n * GOUT + f]);
  else if (f == 15) unsafeAtomicAdd(&cnt[g], 1.0f);
}

__global__ void k_logsoftmax(const float* __restrict__ s, const float* __restrict__ cnt,
                             float* __restrict__ out) {
  int g = blockIdx.x * TPB + threadIdx.x;
  if (g >= NG) return;
  float c = fmaxf(cnt[g], 1.0f);
  float m[GOUT], mx = -1e30f;
#pragma unroll
  for (int j = 0; j < GOUT; ++j) { m[j] = s[g * GOUT + j] / c; mx = fmaxf(mx, m[j]); }
  float sum = 0.0f;
#pragma unroll
  for (int j = 0; j < GOUT; ++j) sum += expf(m[j] - mx);
  float lse = mx + logf(sum);
#pragma unroll
  for (int j = 0; j < GOUT; ++j) out[g * GOUT + j] = m[j] - lse;
}

static inline int cdiv(long a, long b) { return (int)((a + b - 1) / b); }

extern "C" void kernel_launch(void* const* d_in, const int* in_sizes, int n_in,
                              void* d_out, int out_size, void* d_ws, size_t ws_size,
                              hipStream_t stream) {
  const float* x  = (const float*)d_in[0];
  const int*   ei = (const int*)d_in[1];
  const int*   bt = (const int*)d_in[2];
  const float* W1 = (const float*)d_in[3];
  const float* b1 = (const float*)d_in[4];
  const float* W2 = (const float*)d_in[5];
  const float* b2 = (const float*)d_in[6];
  const float* W3 = (const float*)d_in[7];
  const float* b3 = (const float*)d_in[8];
  const float* W4 = (const float*)d_in[9];
  const float* b4 = (const float*)d_in[10];
  float* out = (float*)d_out;

  // workspace layout (floats): dinv[NN] | A[NN*64] | B[NN*64] | S[NG*10] | CNT[NG]
  float* ws   = (float*)d_ws;
  float* dinv = ws;
  float* A    = dinv + NN;
  float* B    = A + (size_t)NN * GH;
  float* S    = B + (size_t)NN * GH;
  float* CNT  = S + (size_t)NG * GOUT;

  const int* row = ei;        // edge_index[0] = source
  const int* col = ei + NE;   // edge_index[1] = target

  // --- degree / dinv ---
  k_zero<<<cdiv(NN, TPB), TPB, 0, stream>>>(dinv, NN);
  k_deg<<<cdiv(NE, TPB), TPB, 0, stream>>>(col, dinv);
  k_dinv<<<cdiv(NN, TPB), TPB, 0, stream>>>(dinv);

  // --- layer 1: x[N,128] -> B[N,64] ---
  k_matmul<GIN, GH, 64><<<cdiv(NN, TPB / 64), TPB, 0, stream>>>(x, W1, A);
  k_selfloop<GH, 64><<<cdiv((long)NN * 64, TPB), TPB, 0, stream>>>(A, dinv, B);
  k_agg<GH, 64><<<cdiv((long)NE * 64, TPB), TPB, 0, stream>>>(row, col, dinv, A, B);
  k_bias<GH, 64, true><<<cdiv((long)NN * 64, TPB), TPB, 0, stream>>>(B, b1);

  // --- layer 2 ---
  k_matmul<GH, GH, 64><<<cdiv(NN, TPB / 64), TPB, 0, stream>>>(B, W2, A);
  k_selfloop<GH, 64><<<cdiv((long)NN * 64, TPB), TPB, 0, stream>>>(A, dinv, B);
  k_agg<GH, 64><<<cdiv((long)NE * 64, TPB), TPB, 0, stream>>>(row, col, dinv, A, B);
  k_bias<GH, 64, true><<<cdiv((long)NN * 64, TPB), TPB, 0, stream>>>(B, b2);

  // --- layer 3 ---
  k_matmul<GH, GH, 64><<<cdiv(NN, TPB / 64), TPB, 0, stream>>>(B, W3, A);
  k_selfloop<GH, 64><<<cdiv((long)NN * 64, TPB), TPB, 0, stream>>>(A, dinv, B);
  k_agg<GH, 64><<<cdiv((long)NE * 64, TPB), TPB, 0, stream>>>(row, col, dinv, A, B);
  k_bias<GH, 64, true><<<cdiv((long)NN * 64, TPB), TPB, 0, stream>>>(B, b3);

  // --- layer 4: B[N,64] -> B[N,10] (no relu) ---
  k_matmul<GH, GOUT, 16><<<cdiv(NN, TPB / 16), TPB, 0, stream>>>(B, W4, A);
  k_selfloop<GOUT, 16><<<cdiv((long)NN * 16, TPB), TPB, 0, stream>>>(A, dinv, B);
  k_agg<GOUT, 16><<<cdiv((long)NE * 16, TPB), TPB, 0, stream>>>(row, col, dinv, A, B);
  k_bias<GOUT, 16, false><<<cdiv((long)NN * 16, TPB), TPB, 0, stream>>>(B, b4);

  // --- pool + log_softmax ---
  k_zero<<<cdiv(NG * GOUT + NG, TPB), TPB, 0, stream>>>(S, NG * GOUT + NG);
  k_pool<<<cdiv((long)NN * 16, TPB), TPB, 0, stream>>>(B, bt, S, CNT);
  k_logsoftmax<<<cdiv(NG, TPB), TPB, 0, stream>>>(S, CNT, out);
}

// Round 2
// 866.844 us; speedup vs baseline: 1.9520x; 1.9520x over previous
//
#include <hip/hip_runtime.h>
#include <math.h>

#define NN 100000
#define NE 1600000
#define GIN 128
#define GH 64
#define GOUT 10
#define NG 512
#define TPB 256
#define SCB 1024              // elements scanned per block in k_scan1
#define NB ((NN + SCB - 1) / SCB)   // 98 scan blocks

__global__ void k_zero_f(float* __restrict__ p, int n) {
  int i = blockIdx.x * TPB + threadIdx.x;
  if (i < n) p[i] = 0.0f;
}

__global__ void k_zero_i(int* __restrict__ p, int n) {
  int i = blockIdx.x * TPB + threadIdx.x;
  if (i < n) p[i] = 0;
}

__global__ void k_hist(const int* __restrict__ col, int* __restrict__ deg) {
  int e = blockIdx.x * TPB + threadIdx.x;
  if (e < NE) atomicAdd(&deg[col[e]], 1);
}

__global__ void k_dinv(const int* __restrict__ deg, float* __restrict__ dinv) {
  int i = blockIdx.x * TPB + threadIdx.x;
  if (i < NN) dinv[i] = rsqrtf((float)deg[i] + 1.0f);  // +1 self-loop
}

// exclusive scan within each SCB-chunk; per-block totals to bsum
__global__ void k_scan1(const int* __restrict__ deg, int* __restrict__ pref,
                        int* __restrict__ bsum) {
  __shared__ int wsum[8];
  int t = threadIdx.x;
  int base = blockIdx.x * SCB;
  int v[4]; int s = 0;
#pragma unroll
  for (int j = 0; j < 4; ++j) {
    int idx = base + t * 4 + j;
    v[j] = (idx < NN) ? deg[idx] : 0;
    s += v[j];
  }
  int lane = t & 63, wid = t >> 6;
  int sc = s;
#pragma unroll
  for (int off = 1; off < 64; off <<= 1) {
    int u = __shfl_up(sc, off);
    if (lane >= off) sc += u;
  }
  if (lane == 63) wsum[wid] = sc;
  __syncthreads();
  if (t == 0) {
    int a = 0;
    for (int w = 0; w < 4; ++w) { int x = wsum[w]; wsum[w] = a; a += x; }
    wsum[4] = a;  // block total
  }
  __syncthreads();
  int excl = sc - s + wsum[wid];
#pragma unroll
  for (int j = 0; j < 4; ++j) {
    int idx = base + t * 4 + j;
    if (idx < NN) pref[idx] = excl;
    excl += v[j];
  }
  if (t == 0) bsum[blockIdx.x] = wsum[4];
}

// exclusive scan of the NB block totals (single block)
__global__ void k_scan2(int* __restrict__ bsum) {
  __shared__ int l[NB];
  int t = threadIdx.x;
  if (t < NB) l[t] = bsum[t];
  __syncthreads();
  if (t == 0) {
    int a = 0;
    for (int i = 0; i < NB; ++i) { int x = l[i]; l[i] = a; a += x; }
  }
  __syncthreads();
  if (t < NB) bsum[t] = l[t];
}

__global__ void k_scan3(const int* __restrict__ pref, const int* __restrict__ bsum,
                        int* __restrict__ rowptr, int* __restrict__ cursor) {
  int i = blockIdx.x * TPB + threadIdx.x;
  if (i < NN) {
    int v = pref[i] + bsum[i / SCB];
    rowptr[i] = v;
    cursor[i] = v;
  }
  if (i == NN) rowptr[NN] = NE;
}

__global__ void k_scatter(const int* __restrict__ row, const int* __restrict__ col,
                          int* __restrict__ cursor, int* __restrict__ esrc) {
  int e = blockIdx.x * TPB + threadIdx.x;
  if (e < NE) {
    int c = col[e];
    int p = atomicAdd(&cursor[c], 1);
    esrc[p] = row[e];
  }
}

// Y[n,f] = (sum_k X[n,k] * W[k,f]) * dinv[n]
template<int K, int D, int LPR>
__global__ void k_matmul(const float* __restrict__ X, const float* __restrict__ W,
                         const float* __restrict__ dinv, float* __restrict__ Y) {
  __shared__ float Wl[K * D];
  for (int i = threadIdx.x; i < K * D; i += TPB) Wl[i] = W[i];
  __syncthreads();
  int n = blockIdx.x * (TPB / LPR) + threadIdx.x / LPR;
  int f = threadIdx.x % LPR;
  if (n >= NN || f >= D) return;
  const float4* xr = (const float4*)(X + (size_t)n * K);
  float acc = 0.0f;
#pragma unroll
  for (int k4 = 0; k4 < K / 4; ++k4) {
    float4 xv = xr[k4];
    acc += xv.x * Wl[(4 * k4 + 0) * D + f];
    acc += xv.y * Wl[(4 * k4 + 1) * D + f];
    acc += xv.z * Wl[(4 * k4 + 2) * D + f];
    acc += xv.w * Wl[(4 * k4 + 3) * D + f];
  }
  Y[(size_t)n * D + f] = acc * dinv[n];
}

// out[n,f] = relu( dinv[n]*(hp[n,f] + sum_{e in in(n)} hp[src,f]) + b[f] )
template<bool RELU>
__global__ void k_agg64(const int* __restrict__ rowptr, const int* __restrict__ esrc,
                        const float* __restrict__ dinv, const float* __restrict__ hp,
                        const float* __restrict__ bias, float* __restrict__ out) {
  int n = blockIdx.x * (TPB / 64) + (threadIdx.x >> 6);
  int f = threadIdx.x & 63;
  if (n >= NN) return;
  int s0 = rowptr[n], s1 = rowptr[n + 1];
  float acc = hp[(size_t)n * 64 + f];
  int e = s0;
  for (; e + 3 < s1; e += 4) {
    int a = esrc[e], b = esrc[e + 1], c = esrc[e + 2], d = esrc[e + 3];
    float va = hp[(size_t)a * 64 + f];
    float vb = hp[(size_t)b * 64 + f];
    float vc = hp[(size_t)c * 64 + f];
    float vd = hp[(size_t)d * 64 + f];
    acc += va; acc += vb; acc += vc; acc += vd;
  }
  for (; e < s1; ++e) acc += hp[(size_t)esrc[e] * 64 + f];
  float v = acc * dinv[n] + bias[f];
  out[(size_t)n * 64 + f] = RELU ? fmaxf(v, 0.0f) : v;
}

// layer-4 aggregation fused with mean-pool accumulation (never materialize [N,10])
__global__ void k_agg10_pool(const int* __restrict__ rowptr, const int* __restrict__ esrc,
                             const float* __restrict__ dinv, const float* __restrict__ hp,
                             const float* __restrict__ bias, const int* __restrict__ batch,
                             float* __restrict__ S, float* __restrict__ CNT) {
  int n = blockIdx.x * (TPB / 16) + (threadIdx.x >> 4);
  int f = threadIdx.x & 15;
  if (n >= NN) return;
  int g = batch[n];
  if (f == 15) { unsafeAtomicAdd(&CNT[g], 1.0f); return; }
  if (f >= GOUT) return;
  int s0 = rowptr[n], s1 = rowptr[n + 1];
  float acc = hp[(size_t)n * GOUT + f];
  int e = s0;
  for (; e + 3 < s1; e += 4) {
    int a = esrc[e], b = esrc[e + 1], c = esrc[e + 2], d = esrc[e + 3];
    acc += hp[(size_t)a * GOUT + f];
    acc += hp[(size_t)b * GOUT + f];
    acc += hp[(size_t)c * GOUT + f];
    acc += hp[(size_t)d * GOUT + f];
  }
  for (; e < s1; ++e) acc += hp[(size_t)esrc[e] * GOUT + f];
  float v = acc * dinv[n] + bias[f];
  unsafeAtomicAdd(&S[g * GOUT + f], v);
}

__global__ void k_logsoftmax(const float* __restrict__ s, const float* __restrict__ cnt,
                             float* __restrict__ out) {
  int g = blockIdx.x * TPB + threadIdx.x;
  if (g >= NG) return;
  float c = fmaxf(cnt[g], 1.0f);
  float m[GOUT], mx = -1e30f;
#pragma unroll
  for (int j = 0; j < GOUT; ++j) { m[j] = s[g * GOUT + j] / c; mx = fmaxf(mx, m[j]); }
  float sum = 0.0f;
#pragma unroll
  for (int j = 0; j < GOUT; ++j) sum += expf(m[j] - mx);
  float lse = mx + logf(sum);
#pragma unroll
  for (int j = 0; j < GOUT; ++j) out[g * GOUT + j] = m[j] - lse;
}

static inline int cdiv(long a, long b) { return (int)((a + b - 1) / b); }

extern "C" void kernel_launch(void* const* d_in, const int* in_sizes, int n_in,
                              void* d_out, int out_size, void* d_ws, size_t ws_size,
                              hipStream_t stream) {
  const float* x  = (const float*)d_in[0];
  const int*   ei = (const int*)d_in[1];
  const int*   bt = (const int*)d_in[2];
  const float* W1 = (const float*)d_in[3];
  const float* b1 = (const float*)d_in[4];
  const float* W2 = (const float*)d_in[5];
  const float* b2 = (const float*)d_in[6];
  const float* W3 = (const float*)d_in[7];
  const float* b3 = (const float*)d_in[8];
  const float* W4 = (const float*)d_in[9];
  const float* b4 = (const float*)d_in[10];
  float* out = (float*)d_out;

  // workspace layout — float arrays first (16B alignment for float4 loads)
  float* A      = (float*)d_ws;              // NN*64
  float* B      = A + (size_t)NN * GH;       // NN*64
  float* dinv   = B + (size_t)NN * GH;       // NN
  float* S      = dinv + NN;                 // NG*GOUT
  float* CNT    = S + NG * GOUT;             // NG
  int*   deg    = (int*)(CNT + NG);          // NN
  int*   pref   = deg + NN;                  // NN
  int*   rowptr = pref + NN;                 // NN+1
  int*   cursor = rowptr + NN + 1;           // NN
  int*   bsum   = cursor + NN;               // NB
  int*   esrc   = bsum + ((NB + 3) & ~3);    // NE

  const int* row = ei;        // edge_index[0] = source
  const int* col = ei + NE;   // edge_index[1] = target

  // --- CSR build + dinv ---
  k_zero_i<<<cdiv(NN, TPB), TPB, 0, stream>>>(deg, NN);
  k_hist<<<cdiv(NE, TPB), TPB, 0, stream>>>(col, deg);
  k_dinv<<<cdiv(NN, TPB), TPB, 0, stream>>>(deg, dinv);
  k_scan1<<<NB, TPB, 0, stream>>>(deg, pref, bsum);
  k_scan2<<<1, TPB, 0, stream>>>(bsum);
  k_scan3<<<cdiv(NN + 1, TPB), TPB, 0, stream>>>(pref, bsum, rowptr, cursor);
  k_scatter<<<cdiv(NE, TPB), TPB, 0, stream>>>(row, col, cursor, esrc);

  // --- layer 1: x[N,128] -> B[N,64] ---
  k_matmul<GIN, GH, 64><<<cdiv(NN, TPB / 64), TPB, 0, stream>>>(x, W1, dinv, A);
  k_agg64<true><<<cdiv(NN, TPB / 64), TPB, 0, stream>>>(rowptr, esrc, dinv, A, b1, B);

  // --- layer 2 ---
  k_matmul<GH, GH, 64><<<cdiv(NN, TPB / 64), TPB, 0, stream>>>(B, W2, dinv, A);
  k_agg64<true><<<cdiv(NN, TPB / 64), TPB, 0, stream>>>(rowptr, esrc, dinv, A, b2, B);

  // --- layer 3 ---
  k_matmul<GH, GH, 64><<<cdiv(NN, TPB / 64), TPB, 0, stream>>>(B, W3, dinv, A);
  k_agg64<true><<<cdiv(NN, TPB / 64), TPB, 0, stream>>>(rowptr, esrc, dinv, A, b3, B);

  // --- layer 4: matmul to [N,10], agg fused with mean-pool accumulation ---
  k_matmul<GH, GOUT, 16><<<cdiv(NN, TPB / 16), TPB, 0, stream>>>(B, W4, dinv, A);
  k_zero_f<<<cdiv(NG * GOUT + NG, TPB), TPB, 0, stream>>>(S, NG * GOUT + NG);
  k_agg10_pool<<<cdiv(NN, TPB / 16), TPB, 0, stream>>>(rowptr, esrc, dinv, A, b4, bt, S, CNT);

  // --- log_softmax ---
  k_logsoftmax<<<cdiv(NG, TPB), TPB, 0, stream>>>(S, CNT, out);
}

// Round 3
// 827.809 us; speedup vs baseline: 2.0440x; 1.0472x over previous
//
#include <hip/hip_runtime.h>
#include <math.h>

#define NN 100000
#define NE 1600000
#define GIN 128
#define GH 64
#define GOUT 10
#define NG 512
#define TPB 256
#define SCB 1024
#define NB ((NN + SCB - 1) / SCB)   // 98 scan blocks

__global__ void k_zero_f(float* __restrict__ p, int n) {
  int i = blockIdx.x * TPB + threadIdx.x;
  if (i < n) p[i] = 0.0f;
}

__global__ void k_zero_i(int* __restrict__ p, int n) {
  int i = blockIdx.x * TPB + threadIdx.x;
  if (i < n) p[i] = 0;
}

__global__ void k_hist(const int* __restrict__ col, int* __restrict__ deg) {
  int e = blockIdx.x * TPB + threadIdx.x;
  if (e < NE) atomicAdd(&deg[col[e]], 1);
}

__global__ void k_dinv(const int* __restrict__ deg, float* __restrict__ dinv) {
  int i = blockIdx.x * TPB + threadIdx.x;
  if (i < NN) dinv[i] = rsqrtf((float)deg[i] + 1.0f);  // +1 self-loop
}

// per-graph node counts via binary search on sorted batch (no atomics)
__global__ void k_cnt(const int* __restrict__ batch, float* __restrict__ cnt) {
  int g = blockIdx.x * TPB + threadIdx.x;
  if (g > NG) return;
  auto lb = [&](int key) {
    int lo = 0, hi = NN;
    while (lo < hi) { int mid = (lo + hi) >> 1; if (batch[mid] < key) lo = mid + 1; else hi = mid; }
    return lo;
  };
  if (g < NG) cnt[g] = (float)(lb(g + 1) - lb(g));
}

// exclusive scan within each SCB-chunk; per-block totals to bsum
__global__ void k_scan1(const int* __restrict__ deg, int* __restrict__ pref,
                        int* __restrict__ bsum) {
  __shared__ int wsum[8];
  int t = threadIdx.x;
  int base = blockIdx.x * SCB;
  int v[4]; int s = 0;
#pragma unroll
  for (int j = 0; j < 4; ++j) {
    int idx = base + t * 4 + j;
    v[j] = (idx < NN) ? deg[idx] : 0;
    s += v[j];
  }
  int lane = t & 63, wid = t >> 6;
  int sc = s;
#pragma unroll
  for (int off = 1; off < 64; off <<= 1) {
    int u = __shfl_up(sc, off);
    if (lane >= off) sc += u;
  }
  if (lane == 63) wsum[wid] = sc;
  __syncthreads();
  if (t == 0) {
    int a = 0;
    for (int w = 0; w < 4; ++w) { int x = wsum[w]; wsum[w] = a; a += x; }
  }
  __syncthreads();
  int excl = sc - s + wsum[wid];
#pragma unroll
  for (int j = 0; j < 4; ++j) {
    int idx = base + t * 4 + j;
    if (idx < NN) pref[idx] = excl;
    excl += v[j];
  }
  __syncthreads();
  if (t == 0) {
    int a = 0;
    for (int w = 0; w < 4; ++w) a += 0;  // (totals already consumed)
  }
  if (t == TPB - 1) bsum[blockIdx.x] = excl;  // excl after last add == block total + block-excl base? no:
  // NOTE: excl at t==TPB-1 after loop = block-exclusive-prefix + all v's = block total (since wsum[wid] excludes nothing beyond block). 
}

// exclusive scan of the NB block totals (single block)
__global__ void k_scan2(int* __restrict__ bsum) {
  __shared__ int l[NB];
  int t = threadIdx.x;
  if (t < NB) l[t] = bsum[t];
  __syncthreads();
  if (t == 0) {
    int a = 0;
    for (int i = 0; i < NB; ++i) { int x = l[i]; l[i] = a; a += x; }
  }
  __syncthreads();
  if (t < NB) bsum[t] = l[t];
}

__global__ void k_scan3(const int* __restrict__ pref, const int* __restrict__ bsum,
                        int* __restrict__ rowptr, int* __restrict__ cursor) {
  int i = blockIdx.x * TPB + threadIdx.x;
  if (i < NN) {
    int v = pref[i] + bsum[i / SCB];
    rowptr[i] = v;
    cursor[i] = v;
  }
  if (i == NN) rowptr[NN] = NE;
}

__global__ void k_scatter(const int* __restrict__ row, const int* __restrict__ col,
                          int* __restrict__ cursor, int* __restrict__ esrc) {
  int e = blockIdx.x * TPB + threadIdx.x;
  if (e < NE) {
    int c = col[e];
    int p = atomicAdd(&cursor[c], 1);
    esrc[p] = row[e];
  }
}

// Y[n,f] = (sum_k X[n,k] * W[k,f]) * dinv[n]
template<int K, int D, int LPR>
__global__ void k_matmul(const float* __restrict__ X, const float* __restrict__ W,
                         const float* __restrict__ dinv, float* __restrict__ Y) {
  __shared__ float Wl[K * D];
  for (int i = threadIdx.x; i < K * D; i += TPB) Wl[i] = W[i];
  __syncthreads();
  int n = blockIdx.x * (TPB / LPR) + threadIdx.x / LPR;
  int f = threadIdx.x % LPR;
  if (n >= NN || f >= D) return;
  const float4* xr = (const float4*)(X + (size_t)n * K);
  float a0 = 0.f, a1 = 0.f, a2 = 0.f, a3 = 0.f;
#pragma unroll
  for (int k4 = 0; k4 < K / 4; ++k4) {
    float4 xv = xr[k4];
    a0 += xv.x * Wl[(4 * k4 + 0) * D + f];
    a1 += xv.y * Wl[(4 * k4 + 1) * D + f];
    a2 += xv.z * Wl[(4 * k4 + 2) * D + f];
    a3 += xv.w * Wl[(4 * k4 + 3) * D + f];
  }
  Y[(size_t)n * D + f] = ((a0 + a1) + (a2 + a3)) * dinv[n];
}

// One wave per node. 4 groups of 16 lanes; group q handles edges s0+q, s0+q+4, ...
// Each lane loads a float4 (features fq*4..fq*4+3). Cross-group shfl reduction.
// SCALE_SRC: multiply each gathered row by dinv[src] (layer-4 path, no matmul before).
// POOL: atomically accumulate z into P[batch[n]*64+f] instead of writing out[n].
template<bool RELU, bool SCALE_SRC, bool POOL>
__global__ void k_agg(const int* __restrict__ rowptr, const int* __restrict__ esrc,
                      const float* __restrict__ dinv, const float* __restrict__ hp,
                      const float* __restrict__ bias, const int* __restrict__ batch,
                      float* __restrict__ out) {
  int n = blockIdx.x * (TPB / 64) + (threadIdx.x >> 6);
  if (n >= NN) return;
  int lane = threadIdx.x & 63;
  int qid = lane >> 4, fq = lane & 15;
  const float4* h4 = (const float4*)hp;
  int s0 = rowptr[n], s1 = rowptr[n + 1];
  float4 acc = {0.f, 0.f, 0.f, 0.f};
  int e = s0 + qid;
  for (; e + 4 < s1; e += 8) {
    int r0 = esrc[e], r1 = esrc[e + 4];
    float4 v0 = h4[(size_t)r0 * 16 + fq];
    float4 v1 = h4[(size_t)r1 * 16 + fq];
    if (SCALE_SRC) {
      float d0 = dinv[r0], d1 = dinv[r1];
      acc.x += v0.x * d0; acc.y += v0.y * d0; acc.z += v0.z * d0; acc.w += v0.w * d0;
      acc.x += v1.x * d1; acc.y += v1.y * d1; acc.z += v1.z * d1; acc.w += v1.w * d1;
    } else {
      acc.x += v0.x; acc.y += v0.y; acc.z += v0.z; acc.w += v0.w;
      acc.x += v1.x; acc.y += v1.y; acc.z += v1.z; acc.w += v1.w;
    }
  }
  if (e < s1) {
    int r = esrc[e];
    float4 v = h4[(size_t)r * 16 + fq];
    float d = SCALE_SRC ? dinv[r] : 1.0f;
    acc.x += v.x * d; acc.y += v.y * d; acc.z += v.z * d; acc.w += v.w * d;
  }
#define RED(o) acc.x += __shfl_xor(acc.x, o); acc.y += __shfl_xor(acc.y, o); \
               acc.z += __shfl_xor(acc.z, o); acc.w += __shfl_xor(acc.w, o);
  RED(16) RED(32)
#undef RED
  if (qid == 0) {
    float dn = dinv[n];
    float4 self = h4[(size_t)n * 16 + fq];
    float sc = SCALE_SRC ? dn : 1.0f;
    float4 r;
    r.x = (acc.x + self.x * sc) * dn;
    r.y = (acc.y + self.y * sc) * dn;
    r.z = (acc.z + self.z * sc) * dn;
    r.w = (acc.w + self.w * sc) * dn;
    if (!POOL) {
      float4 bv = ((const float4*)bias)[fq];
      r.x += bv.x; r.y += bv.y; r.z += bv.z; r.w += bv.w;
      if (RELU) {
        r.x = fmaxf(r.x, 0.f); r.y = fmaxf(r.y, 0.f);
        r.z = fmaxf(r.z, 0.f); r.w = fmaxf(r.w, 0.f);
      }
      ((float4*)out)[(size_t)n * 16 + fq] = r;
    } else {
      int g = batch[n];
      float* pr = out + (size_t)g * 64 + fq * 4;
      unsafeAtomicAdd(pr + 0, r.x);
      unsafeAtomicAdd(pr + 1, r.y);
      unsafeAtomicAdd(pr + 2, r.z);
      unsafeAtomicAdd(pr + 3, r.w);
    }
  }
}

// per graph: pooled = P[g]/cnt[g]; t = pooled @ W4 + b4; out = log_softmax(t)
__global__ void k_head(const float* __restrict__ P, const float* __restrict__ cnt,
                       const float* __restrict__ W4, const float* __restrict__ b4,
                       float* __restrict__ out) {
  int g = blockIdx.x;
  int lane = threadIdx.x;  // 64
  float p = P[(size_t)g * 64 + lane] / fmaxf(cnt[g], 1.0f);
  float t[GOUT];
#pragma unroll
  for (int j = 0; j < GOUT; ++j) {
    float r = p * W4[lane * GOUT + j];
#pragma unroll
    for (int off = 1; off < 64; off <<= 1) r += __shfl_xor(r, off);
    t[j] = r + b4[j];
  }
  if (lane == 0) {
    float mx = -1e30f;
#pragma unroll
    for (int j = 0; j < GOUT; ++j) mx = fmaxf(mx, t[j]);
    float sum = 0.f;
#pragma unroll
    for (int j = 0; j < GOUT; ++j) sum += expf(t[j] - mx);
    float lse = mx + logf(sum);
#pragma unroll
    for (int j = 0; j < GOUT; ++j) out[(size_t)g * GOUT + j] = t[j] - lse;
  }
}

static inline int cdiv(long a, long b) { return (int)((a + b - 1) / b); }

extern "C" void kernel_launch(void* const* d_in, const int* in_sizes, int n_in,
                              void* d_out, int out_size, void* d_ws, size_t ws_size,
                              hipStream_t stream) {
  const float* x  = (const float*)d_in[0];
  const int*   ei = (const int*)d_in[1];
  const int*   bt = (const int*)d_in[2];
  const float* W1 = (const float*)d_in[3];
  const float* b1 = (const float*)d_in[4];
  const float* W2 = (const float*)d_in[5];
  const float* b2 = (const float*)d_in[6];
  const float* W3 = (const float*)d_in[7];
  const float* b3 = (const float*)d_in[8];
  const float* W4 = (const float*)d_in[9];
  const float* b4 = (const float*)d_in[10];
  float* out = (float*)d_out;

  // workspace: float arrays first (16B alignment for float4)
  float* A      = (float*)d_ws;              // NN*64
  float* B      = A + (size_t)NN * GH;       // NN*64
  float* dinv   = B + (size_t)NN * GH;       // NN
  float* P      = dinv + NN;                 // NG*64
  float* CNT    = P + (size_t)NG * GH;       // NG
  int*   deg    = (int*)(CNT + NG);          // NN
  int*   pref   = deg + NN;                  // NN
  int*   rowptr = pref + NN;                 // NN+1
  int*   cursor = rowptr + NN + 1;           // NN
  int*   bsum   = cursor + NN;               // NB
  int*   esrc   = bsum + ((NB + 3) & ~3);    // NE

  const int* row = ei;        // edge_index[0] = source
  const int* col = ei + NE;   // edge_index[1] = target (aggregate here)

  // --- CSR build + dinv + per-graph counts ---
  k_zero_i<<<cdiv(NN, TPB), TPB, 0, stream>>>(deg, NN);
  k_hist<<<cdiv(NE, TPB), TPB, 0, stream>>>(col, deg);
  k_dinv<<<cdiv(NN, TPB), TPB, 0, stream>>>(deg, dinv);
  k_cnt<<<cdiv(NG + 1, TPB), TPB, 0, stream>>>(bt, CNT);
  k_scan1<<<NB, TPB, 0, stream>>>(deg, pref, bsum);
  k_scan2<<<1, TPB, 0, stream>>>(bsum);
  k_scan3<<<cdiv(NN + 1, TPB), TPB, 0, stream>>>(pref, bsum, rowptr, cursor);
  k_scatter<<<cdiv(NE, TPB), TPB, 0, stream>>>(row, col, cursor, esrc);

  // --- layer 1: x[N,128] -> B[N,64] ---
  k_matmul<GIN, GH, 64><<<cdiv(NN, TPB / 64), TPB, 0, stream>>>(x, W1, dinv, A);
  k_agg<true, false, false><<<cdiv(NN, TPB / 64), TPB, 0, stream>>>(rowptr, esrc, dinv, A, b1, bt, B);

  // --- layer 2 ---
  k_matmul<GH, GH, 64><<<cdiv(NN, TPB / 64), TPB, 0, stream>>>(B, W2, dinv, A);
  k_agg<true, false, false><<<cdiv(NN, TPB / 64), TPB, 0, stream>>>(rowptr, esrc, dinv, A, b2, bt, B);

  // --- layer 3 ---
  k_matmul<GH, GH, 64><<<cdiv(NN, TPB / 64), TPB, 0, stream>>>(B, W3, dinv, A);
  k_agg<true, false, false><<<cdiv(NN, TPB / 64), TPB, 0, stream>>>(rowptr, esrc, dinv, A, b3, bt, B);

  // --- layer 4 (algebraic swap): P[g] = sum_{n in g} (Â·H3)[n]; head does @W4+b4 ---
  k_zero_f<<<cdiv(NG * GH, TPB), TPB, 0, stream>>>(P, NG * GH);
  k_agg<false, true, true><<<cdiv(NN, TPB / 64), TPB, 0, stream>>>(rowptr, esrc, dinv, B, nullptr, bt, P);

  // --- head: mean, W4, b4, log_softmax ---
  k_head<<<NG, 64, 0, stream>>>(P, CNT, W4, b4, out);
}

// Round 4
// 629.549 us; speedup vs baseline: 2.6877x; 1.3149x over previous
//
#include <hip/hip_runtime.h>
#include <math.h>
#include <stdint.h>

#define NN 100000
#define NE 1600000
#define GIN 128
#define GH 64
#define GOUT 10
#define NG 512
#define TPB 256
#define SCB 1024
#define NB ((NN + SCB - 1) / SCB)   // 98 scan blocks

// ---- bf16 helpers (RNE pack) ----
__device__ __forceinline__ float bflo(uint32_t u) { return __uint_as_float(u << 16); }
__device__ __forceinline__ float bfhi(uint32_t u) { return __uint_as_float(u & 0xFFFF0000u); }
__device__ __forceinline__ uint32_t f2bf(float f) {
  uint32_t b = __float_as_uint(f);
  return (b + 0x7FFFu + ((b >> 16) & 1u)) >> 16;
}
__device__ __forceinline__ uint32_t pack2(float lo, float hi) { return f2bf(lo) | (f2bf(hi) << 16); }

__global__ void k_zero_i(int* __restrict__ p, int n) {
  int i = blockIdx.x * TPB + threadIdx.x;
  if (i < n) p[i] = 0;
}

__global__ void k_hist(const int* __restrict__ col, int* __restrict__ deg) {
  int e = blockIdx.x * TPB + threadIdx.x;
  if (e < NE) atomicAdd(&deg[col[e]], 1);
}

__global__ void k_dinv(const int* __restrict__ deg, float* __restrict__ dinv) {
  int i = blockIdx.x * TPB + threadIdx.x;
  if (i < NN) dinv[i] = rsqrtf((float)deg[i] + 1.0f);  // +1 self-loop
}

// gstart[g] = first node index with batch >= g (batch is sorted); gstart[NG] = NN
__global__ void k_gstart(const int* __restrict__ batch, int* __restrict__ gstart) {
  int g = blockIdx.x * TPB + threadIdx.x;
  if (g > NG) return;
  int lo = 0, hi = NN;
  while (lo < hi) { int mid = (lo + hi) >> 1; if (batch[mid] < g) lo = mid + 1; else hi = mid; }
  gstart[g] = lo;
}

// exclusive scan within each SCB-chunk; per-block totals to bsum
__global__ void k_scan1(const int* __restrict__ deg, int* __restrict__ pref,
                        int* __restrict__ bsum) {
  __shared__ int wsum[8];
  int t = threadIdx.x;
  int base = blockIdx.x * SCB;
  int v[4]; int s = 0;
#pragma unroll
  for (int j = 0; j < 4; ++j) {
    int idx = base + t * 4 + j;
    v[j] = (idx < NN) ? deg[idx] : 0;
    s += v[j];
  }
  int lane = t & 63, wid = t >> 6;
  int sc = s;
#pragma unroll
  for (int off = 1; off < 64; off <<= 1) {
    int u = __shfl_up(sc, off);
    if (lane >= off) sc += u;
  }
  if (lane == 63) wsum[wid] = sc;
  __syncthreads();
  if (t == 0) {
    int a = 0;
    for (int w = 0; w < 4; ++w) { int x = wsum[w]; wsum[w] = a; a += x; }
  }
  __syncthreads();
  int excl = sc - s + wsum[wid];
#pragma unroll
  for (int j = 0; j < 4; ++j) {
    int idx = base + t * 4 + j;
    if (idx < NN) pref[idx] = excl;
    excl += v[j];
  }
  if (t == TPB - 1) bsum[blockIdx.x] = excl;  // block total
}

__global__ void k_scan2(int* __restrict__ bsum) {
  __shared__ int l[NB];
  int t = threadIdx.x;
  if (t < NB) l[t] = bsum[t];
  __syncthreads();
  if (t == 0) {
    int a = 0;
    for (int i = 0; i < NB; ++i) { int x = l[i]; l[i] = a; a += x; }
  }
  __syncthreads();
  if (t < NB) bsum[t] = l[t];
}

__global__ void k_scan3(const int* __restrict__ pref, const int* __restrict__ bsum,
                        int* __restrict__ rowptr, int* __restrict__ cursor) {
  int i = blockIdx.x * TPB + threadIdx.x;
  if (i < NN) {
    int v = pref[i] + bsum[i / SCB];
    rowptr[i] = v;
    cursor[i] = v;
  }
  if (i == NN) rowptr[NN] = NE;
}

__global__ void k_scatter(const int* __restrict__ row, const int* __restrict__ col,
                          int* __restrict__ cursor, int* __restrict__ esrc) {
  int e = blockIdx.x * TPB + threadIdx.x;
  if (e < NE) {
    int c = col[e];
    int p = atomicAdd(&cursor[c], 1);
    esrc[p] = row[e];
  }
}

// Y[n,f] = bf16( (sum_k X[n,k]*W[k,f]) * dinv[n] ), X f32 [N,K]
template<int K, int D>
__global__ void k_matmul_f32(const float* __restrict__ X, const float* __restrict__ W,
                             const float* __restrict__ dinv, ushort* __restrict__ Y) {
  __shared__ float Wl[K * D];
  for (int i = threadIdx.x; i < K * D; i += TPB) Wl[i] = W[i];
  __syncthreads();
  int n = blockIdx.x * (TPB / 64) + (threadIdx.x >> 6);
  int f = threadIdx.x & 63;
  if (n >= NN) return;
  const float4* xr = (const float4*)(X + (size_t)n * K);
  float a0 = 0.f, a1 = 0.f, a2 = 0.f, a3 = 0.f;
#pragma unroll
  for (int k4 = 0; k4 < K / 4; ++k4) {
    float4 xv = xr[k4];
    a0 += xv.x * Wl[(4 * k4 + 0) * D + f];
    a1 += xv.y * Wl[(4 * k4 + 1) * D + f];
    a2 += xv.z * Wl[(4 * k4 + 2) * D + f];
    a3 += xv.w * Wl[(4 * k4 + 3) * D + f];
  }
  Y[(size_t)n * D + f] = (ushort)f2bf(((a0 + a1) + (a2 + a3)) * dinv[n]);
}

// Y[n,f] = bf16( (sum_k X[n,k]*W[k,f]) * dinv[n] ), X bf16 [N,64]
__global__ void k_matmul_bf(const ushort* __restrict__ X, const float* __restrict__ W,
                            const float* __restrict__ dinv, ushort* __restrict__ Y) {
  __shared__ float Wl[GH * GH];
  for (int i = threadIdx.x; i < GH * GH; i += TPB) Wl[i] = W[i];
  __syncthreads();
  int n = blockIdx.x * (TPB / 64) + (threadIdx.x >> 6);
  int f = threadIdx.x & 63;
  if (n >= NN) return;
  const uint4* xr = (const uint4*)(X + (size_t)n * GH);
  float acc = 0.f;
#pragma unroll
  for (int k4 = 0; k4 < GH / 8; ++k4) {
    uint4 xv = xr[k4];
    int kb = k4 * 8;
    acc += bflo(xv.x) * Wl[(kb + 0) * GH + f];
    acc += bfhi(xv.x) * Wl[(kb + 1) * GH + f];
    acc += bflo(xv.y) * Wl[(kb + 2) * GH + f];
    acc += bfhi(xv.y) * Wl[(kb + 3) * GH + f];
    acc += bflo(xv.z) * Wl[(kb + 4) * GH + f];
    acc += bfhi(xv.z) * Wl[(kb + 5) * GH + f];
    acc += bflo(xv.w) * Wl[(kb + 6) * GH + f];
    acc += bfhi(xv.w) * Wl[(kb + 7) * GH + f];
  }
  Y[(size_t)n * GH + f] = (ushort)f2bf(acc * dinv[n]);
}

// One wave per node; 8 groups of 8 lanes; group q handles edges s0+q, s0+q+8, ...
// Each lane loads uint4 = 8 bf16 feats (feats fq*8..fq*8+7). 128 B/row gathers.
// acc in f32; cross-group shfl reduction; qid==0 lanes write bf16 row.
template<bool RELU, bool SCALE_SRC, bool BIAS>
__global__ void k_agg(const int* __restrict__ rowptr, const int* __restrict__ esrc,
                      const float* __restrict__ dinv, const uint4* __restrict__ hp,
                      const float* __restrict__ bias, uint4* __restrict__ out) {
  int n = blockIdx.x * (TPB / 64) + (threadIdx.x >> 6);
  if (n >= NN) return;
  int lane = threadIdx.x & 63;
  int qid = lane >> 3, fq = lane & 7;
  int s0 = rowptr[n], s1 = rowptr[n + 1];
  float acc[8] = {0.f, 0.f, 0.f, 0.f, 0.f, 0.f, 0.f, 0.f};
  int e = s0 + qid;
  for (; e + 8 < s1; e += 16) {
    int r0 = esrc[e], r1 = esrc[e + 8];
    uint4 v0 = hp[(size_t)r0 * 8 + fq];
    uint4 v1 = hp[(size_t)r1 * 8 + fq];
    float d0 = 1.f, d1 = 1.f;
    if (SCALE_SRC) { d0 = dinv[r0]; d1 = dinv[r1]; }
    acc[0] += bflo(v0.x) * d0; acc[1] += bfhi(v0.x) * d0;
    acc[2] += bflo(v0.y) * d0; acc[3] += bfhi(v0.y) * d0;
    acc[4] += bflo(v0.z) * d0; acc[5] += bfhi(v0.z) * d0;
    acc[6] += bflo(v0.w) * d0; acc[7] += bfhi(v0.w) * d0;
    acc[0] += bflo(v1.x) * d1; acc[1] += bfhi(v1.x) * d1;
    acc[2] += bflo(v1.y) * d1; acc[3] += bfhi(v1.y) * d1;
    acc[4] += bflo(v1.z) * d1; acc[5] += bfhi(v1.z) * d1;
    acc[6] += bflo(v1.w) * d1; acc[7] += bfhi(v1.w) * d1;
  }
  if (e < s1) {
    int r = esrc[e];
    uint4 v = hp[(size_t)r * 8 + fq];
    float d = SCALE_SRC ? dinv[r] : 1.f;
    acc[0] += bflo(v.x) * d; acc[1] += bfhi(v.x) * d;
    acc[2] += bflo(v.y) * d; acc[3] += bfhi(v.y) * d;
    acc[4] += bflo(v.z) * d; acc[5] += bfhi(v.z) * d;
    acc[6] += bflo(v.w) * d; acc[7] += bfhi(v.w) * d;
  }
#pragma unroll
  for (int off = 8; off < 64; off <<= 1) {
#pragma unroll
    for (int i = 0; i < 8; ++i) acc[i] += __shfl_xor(acc[i], off);
  }
  if (qid == 0) {
    float dn = dinv[n];
    uint4 sv = hp[(size_t)n * 8 + fq];
    float sc = SCALE_SRC ? dn : 1.f;
    float r[8];
    r[0] = (acc[0] + bflo(sv.x) * sc) * dn; r[1] = (acc[1] + bfhi(sv.x) * sc) * dn;
    r[2] = (acc[2] + bflo(sv.y) * sc) * dn; r[3] = (acc[3] + bfhi(sv.y) * sc) * dn;
    r[4] = (acc[4] + bflo(sv.z) * sc) * dn; r[5] = (acc[5] + bfhi(sv.z) * sc) * dn;
    r[6] = (acc[6] + bflo(sv.w) * sc) * dn; r[7] = (acc[7] + bfhi(sv.w) * sc) * dn;
    if (BIAS) {
      const float4* b4p = (const float4*)bias;
      float4 bA = b4p[fq * 2], bB = b4p[fq * 2 + 1];
      r[0] += bA.x; r[1] += bA.y; r[2] += bA.z; r[3] += bA.w;
      r[4] += bB.x; r[5] += bB.y; r[6] += bB.z; r[7] += bB.w;
    }
    if (RELU) {
#pragma unroll
      for (int i = 0; i < 8; ++i) r[i] = fmaxf(r[i], 0.f);
    }
    uint4 o;
    o.x = pack2(r[0], r[1]); o.y = pack2(r[2], r[3]);
    o.z = pack2(r[4], r[5]); o.w = pack2(r[6], r[7]);
    out[(size_t)n * 8 + fq] = o;
  }
}

// per-graph segmented sum over sorted batch: P[g,f] = sum_{n in g} agg4[n,f]
__global__ void k_pool(const ushort* __restrict__ agg4, const int* __restrict__ gstart,
                       float* __restrict__ P) {
  __shared__ float part[4][GH];
  int g = blockIdx.x;
  int f = threadIdx.x & 63, r = threadIdx.x >> 6;  // 4 row-streams
  int a = gstart[g], b = gstart[g + 1];
  float acc = 0.f;
  for (int n = a + r; n < b; n += 4)
    acc += __uint_as_float(((uint32_t)agg4[(size_t)n * GH + f]) << 16);
  part[r][f] = acc;
  __syncthreads();
  if (r == 0) P[(size_t)g * GH + f] = part[0][f] + part[1][f] + part[2][f] + part[3][f];
}

// per graph: pooled = P[g]/cnt; t = pooled@W4 + b4; out = log_softmax(t)
__global__ void k_head(const float* __restrict__ P, const int* __restrict__ gstart,
                       const float* __restrict__ W4, const float* __restrict__ b4,
                       float* __restrict__ out) {
  int g = blockIdx.x;
  int lane = threadIdx.x;  // 64
  float c = fmaxf((float)(gstart[g + 1] - gstart[g]), 1.0f);
  float p = P[(size_t)g * GH + lane] / c;
  float t[GOUT];
#pragma unroll
  for (int j = 0; j < GOUT; ++j) {
    float r = p * W4[lane * GOUT + j];
#pragma unroll
    for (int off = 1; off < 64; off <<= 1) r += __shfl_xor(r, off);
    t[j] = r + b4[j];
  }
  if (lane == 0) {
    float mx = -1e30f;
#pragma unroll
    for (int j = 0; j < GOUT; ++j) mx = fmaxf(mx, t[j]);
    float sum = 0.f;
#pragma unroll
    for (int j = 0; j < GOUT; ++j) sum += expf(t[j] - mx);
    float lse = mx + logf(sum);
#pragma unroll
    for (int j = 0; j < GOUT; ++j) out[(size_t)g * GOUT + j] = t[j] - lse;
  }
}

static inline int cdiv(long a, long b) { return (int)((a + b - 1) / b); }

extern "C" void kernel_launch(void* const* d_in, const int* in_sizes, int n_in,
                              void* d_out, int out_size, void* d_ws, size_t ws_size,
                              hipStream_t stream) {
  const float* x  = (const float*)d_in[0];
  const int*   ei = (const int*)d_in[1];
  const int*   bt = (const int*)d_in[2];
  const float* W1 = (const float*)d_in[3];
  const float* b1 = (const float*)d_in[4];
  const float* W2 = (const float*)d_in[5];
  const float* b2 = (const float*)d_in[6];
  const float* W3 = (const float*)d_in[7];
  const float* b3 = (const float*)d_in[8];
  const float* W4 = (const float*)d_in[9];
  const float* b4 = (const float*)d_in[10];
  float* out = (float*)d_out;

  // workspace: bf16 tables first (16B aligned)
  ushort* HP   = (ushort*)d_ws;                       // NN*64 bf16 (matmul out / L4 agg out)
  ushort* ACT  = HP + (size_t)NN * GH;                // NN*64 bf16 (agg out / matmul in)
  float* dinv  = (float*)(ACT + (size_t)NN * GH);     // NN
  float* P     = dinv + NN;                           // NG*64
  int* gstart  = (int*)(P + (size_t)NG * GH);         // NG+1
  int* deg     = gstart + NG + 3;                     // NN
  int* pref    = deg + NN;                            // NN
  int* rowptr  = pref + NN;                           // NN+1
  int* cursor  = rowptr + NN + 1;                     // NN
  int* bsum    = cursor + NN;                         // NB
  int* esrc    = bsum + ((NB + 3) & ~3);              // NE

  const int* row = ei;        // edge_index[0] = source
  const int* col = ei + NE;   // edge_index[1] = target (aggregate here)

  // --- CSR build + dinv + graph starts ---
  k_zero_i<<<cdiv(NN, TPB), TPB, 0, stream>>>(deg, NN);
  k_hist<<<cdiv(NE, TPB), TPB, 0, stream>>>(col, deg);
  k_dinv<<<cdiv(NN, TPB), TPB, 0, stream>>>(deg, dinv);
  k_gstart<<<cdiv(NG + 1, TPB), TPB, 0, stream>>>(bt, gstart);
  k_scan1<<<NB, TPB, 0, stream>>>(deg, pref, bsum);
  k_scan2<<<1, TPB, 0, stream>>>(bsum);
  k_scan3<<<cdiv(NN + 1, TPB), TPB, 0, stream>>>(pref, bsum, rowptr, cursor);
  k_scatter<<<cdiv(NE, TPB), TPB, 0, stream>>>(row, col, cursor, esrc);

  const int gridN = cdiv(NN, TPB / 64);

  // --- layer 1 ---
  k_matmul_f32<GIN, GH><<<gridN, TPB, 0, stream>>>(x, W1, dinv, HP);
  k_agg<true, false, true><<<gridN, TPB, 0, stream>>>(rowptr, esrc, dinv, (const uint4*)HP, b1, (uint4*)ACT);
  // --- layer 2 ---
  k_matmul_bf<<<gridN, TPB, 0, stream>>>(ACT, W2, dinv, HP);
  k_agg<true, false, true><<<gridN, TPB, 0, stream>>>(rowptr, esrc, dinv, (const uint4*)HP, b2, (uint4*)ACT);
  // --- layer 3 ---
  k_matmul_bf<<<gridN, TPB, 0, stream>>>(ACT, W3, dinv, HP);
  k_agg<true, false, true><<<gridN, TPB, 0, stream>>>(rowptr, esrc, dinv, (const uint4*)HP, b3, (uint4*)ACT);
  // --- layer 4 (algebraic swap): AGG4 = Â·H3 into HP (bf16), no bias/relu ---
  k_agg<false, true, false><<<gridN, TPB, 0, stream>>>(rowptr, esrc, dinv, (const uint4*)ACT, nullptr, (uint4*)HP);

  // --- pool + head ---
  k_pool<<<NG, TPB, 0, stream>>>(HP, gstart, P);
  k_head<<<NG, 64, 0, stream>>>(P, gstart, W4, b4, out);
}

// Round 5
// 602.944 us; speedup vs baseline: 2.8063x; 1.0441x over previous
//
#include <hip/hip_runtime.h>
#include <math.h>
#include <stdint.h>

#define NN 100000
#define NE 1600000
#define GIN 128
#define GH 64
#define GOUT 10
#define NG 512
#define TPB 256
#define SCB 1024
#define NB ((NN + SCB - 1) / SCB)   // 98 scan blocks
#define MMBLK 1024                  // blocks for register-W matmul (4096 waves)

// ---- bf16 helpers (RNE pack) ----
__device__ __forceinline__ float bflo(uint32_t u) { return __uint_as_float(u << 16); }
__device__ __forceinline__ float bfhi(uint32_t u) { return __uint_as_float(u & 0xFFFF0000u); }
__device__ __forceinline__ uint32_t f2bf(float f) {
  uint32_t b = __float_as_uint(f);
  return (b + 0x7FFFu + ((b >> 16) & 1u)) >> 16;
}
__device__ __forceinline__ uint32_t pack2(float lo, float hi) { return f2bf(lo) | (f2bf(hi) << 16); }

__global__ void k_zero_i(int* __restrict__ p, int n) {
  int i = blockIdx.x * TPB + threadIdx.x;
  if (i < n) p[i] = 0;
}

__global__ void k_hist(const int* __restrict__ col, int* __restrict__ deg) {
  int e = blockIdx.x * TPB + threadIdx.x;
  if (e < NE) atomicAdd(&deg[col[e]], 1);
}

__global__ void k_dinv(const int* __restrict__ deg, float* __restrict__ dinv) {
  int i = blockIdx.x * TPB + threadIdx.x;
  if (i < NN) dinv[i] = rsqrtf((float)deg[i] + 1.0f);  // +1 self-loop
}

// gstart[g] = first node index with batch >= g (batch sorted); gstart[NG] = NN
__global__ void k_gstart(const int* __restrict__ batch, int* __restrict__ gstart) {
  int g = blockIdx.x * TPB + threadIdx.x;
  if (g > NG) return;
  int lo = 0, hi = NN;
  while (lo < hi) { int mid = (lo + hi) >> 1; if (batch[mid] < g) lo = mid + 1; else hi = mid; }
  gstart[g] = lo;
}

__global__ void k_scan1(const int* __restrict__ deg, int* __restrict__ pref,
                        int* __restrict__ bsum) {
  __shared__ int wsum[8];
  int t = threadIdx.x;
  int base = blockIdx.x * SCB;
  int v[4]; int s = 0;
#pragma unroll
  for (int j = 0; j < 4; ++j) {
    int idx = base + t * 4 + j;
    v[j] = (idx < NN) ? deg[idx] : 0;
    s += v[j];
  }
  int lane = t & 63, wid = t >> 6;
  int sc = s;
#pragma unroll
  for (int off = 1; off < 64; off <<= 1) {
    int u = __shfl_up(sc, off);
    if (lane >= off) sc += u;
  }
  if (lane == 63) wsum[wid] = sc;
  __syncthreads();
  if (t == 0) {
    int a = 0;
    for (int w = 0; w < 4; ++w) { int x = wsum[w]; wsum[w] = a; a += x; }
  }
  __syncthreads();
  int excl = sc - s + wsum[wid];
#pragma unroll
  for (int j = 0; j < 4; ++j) {
    int idx = base + t * 4 + j;
    if (idx < NN) pref[idx] = excl;
    excl += v[j];
  }
  if (t == TPB - 1) bsum[blockIdx.x] = excl;  // block total
}

__global__ void k_scan2(int* __restrict__ bsum) {
  __shared__ int l[NB];
  int t = threadIdx.x;
  if (t < NB) l[t] = bsum[t];
  __syncthreads();
  if (t == 0) {
    int a = 0;
    for (int i = 0; i < NB; ++i) { int x = l[i]; l[i] = a; a += x; }
  }
  __syncthreads();
  if (t < NB) bsum[t] = l[t];
}

__global__ void k_scan3(const int* __restrict__ pref, const int* __restrict__ bsum,
                        int* __restrict__ rowptr, int* __restrict__ cursor) {
  int i = blockIdx.x * TPB + threadIdx.x;
  if (i < NN) {
    int v = pref[i] + bsum[i / SCB];
    rowptr[i] = v;
    cursor[i] = v;
  }
  if (i == NN) rowptr[NN] = NE;
}

__global__ void k_scatter(const int* __restrict__ row, const int* __restrict__ col,
                          int* __restrict__ cursor, int* __restrict__ esrc) {
  int e = blockIdx.x * TPB + threadIdx.x;
  if (e < NE) {
    int c = col[e];
    int p = atomicAdd(&cursor[c], 1);
    esrc[p] = row[e];
  }
}

// ---- register-W matmul, f32 input: Y[n,f] = bf16((sum_k X[n,k]W[k,f])*dinv[n]) ----
// lane = feature f; W column in VGPRs; x-row broadcast loads; no LDS.
__global__ __launch_bounds__(TPB, 2)
void k_mm_f32(const float* __restrict__ X, const float* __restrict__ W,
              const float* __restrict__ dinv, ushort* __restrict__ Y) {
  int lane = threadIdx.x & 63;
  int wid = blockIdx.x * (TPB / 64) + (threadIdx.x >> 6);
  int nw = MMBLK * (TPB / 64);
  float w[GIN];
#pragma unroll
  for (int k = 0; k < GIN; ++k) w[k] = W[k * GH + lane];
  for (int n0 = wid * 2; n0 < NN; n0 += nw * 2) {
    int n1 = n0 + 1;
    bool has1 = n1 < NN;
    const float4* x0 = (const float4*)(X + (size_t)n0 * GIN);
    const float4* x1 = (const float4*)(X + (size_t)(has1 ? n1 : n0) * GIN);
    float a0 = 0.f, a1 = 0.f;
#pragma unroll
    for (int k4 = 0; k4 < GIN / 4; ++k4) {
      float4 v0 = x0[k4], v1 = x1[k4];
      a0 += v0.x * w[4 * k4 + 0]; a1 += v1.x * w[4 * k4 + 0];
      a0 += v0.y * w[4 * k4 + 1]; a1 += v1.y * w[4 * k4 + 1];
      a0 += v0.z * w[4 * k4 + 2]; a1 += v1.z * w[4 * k4 + 2];
      a0 += v0.w * w[4 * k4 + 3]; a1 += v1.w * w[4 * k4 + 3];
    }
    Y[(size_t)n0 * GH + lane] = (ushort)f2bf(a0 * dinv[n0]);
    if (has1) Y[(size_t)n1 * GH + lane] = (ushort)f2bf(a1 * dinv[n1]);
  }
}

// ---- register-W matmul, bf16 input [N,64] ----
__global__ __launch_bounds__(TPB, 2)
void k_mm_bf(const ushort* __restrict__ X, const float* __restrict__ W,
             const float* __restrict__ dinv, ushort* __restrict__ Y) {
  int lane = threadIdx.x & 63;
  int wid = blockIdx.x * (TPB / 64) + (threadIdx.x >> 6);
  int nw = MMBLK * (TPB / 64);
  float w[GH];
#pragma unroll
  for (int k = 0; k < GH; ++k) w[k] = W[k * GH + lane];
  for (int n0 = wid * 2; n0 < NN; n0 += nw * 2) {
    int n1 = n0 + 1;
    bool has1 = n1 < NN;
    const uint4* x0 = (const uint4*)(X + (size_t)n0 * GH);
    const uint4* x1 = (const uint4*)(X + (size_t)(has1 ? n1 : n0) * GH);
    float a0 = 0.f, a1 = 0.f;
#pragma unroll
    for (int k8 = 0; k8 < GH / 8; ++k8) {
      uint4 v0 = x0[k8], v1 = x1[k8];
      int kb = k8 * 8;
      a0 += bflo(v0.x) * w[kb + 0]; a1 += bflo(v1.x) * w[kb + 0];
      a0 += bfhi(v0.x) * w[kb + 1]; a1 += bfhi(v1.x) * w[kb + 1];
      a0 += bflo(v0.y) * w[kb + 2]; a1 += bflo(v1.y) * w[kb + 2];
      a0 += bfhi(v0.y) * w[kb + 3]; a1 += bfhi(v1.y) * w[kb + 3];
      a0 += bflo(v0.z) * w[kb + 4]; a1 += bflo(v1.z) * w[kb + 4];
      a0 += bfhi(v0.z) * w[kb + 5]; a1 += bfhi(v1.z) * w[kb + 5];
      a0 += bflo(v0.w) * w[kb + 6]; a1 += bflo(v1.w) * w[kb + 6];
      a0 += bfhi(v0.w) * w[kb + 7]; a1 += bfhi(v1.w) * w[kb + 7];
    }
    Y[(size_t)n0 * GH + lane] = (ushort)f2bf(a0 * dinv[n0]);
    if (has1) Y[(size_t)n1 * GH + lane] = (ushort)f2bf(a1 * dinv[n1]);
  }
}

// One wave per node; 8 groups of 8 lanes; group q handles edges s0+q, s0+q+8, ...
// Each lane loads uint4 = 8 bf16 feats. acc f32; cross-group shfl reduction.
template<bool RELU, bool SCALE_SRC, bool BIAS>
__global__ void k_agg(const int* __restrict__ rowptr, const int* __restrict__ esrc,
                      const float* __restrict__ dinv, const uint4* __restrict__ hp,
                      const float* __restrict__ bias, uint4* __restrict__ out) {
  int n = blockIdx.x * (TPB / 64) + (threadIdx.x >> 6);
  if (n >= NN) return;
  int lane = threadIdx.x & 63;
  int qid = lane >> 3, fq = lane & 7;
  int s0 = rowptr[n], s1 = rowptr[n + 1];
  float acc[8] = {0.f, 0.f, 0.f, 0.f, 0.f, 0.f, 0.f, 0.f};
  int e = s0 + qid;
  for (; e + 8 < s1; e += 16) {
    int r0 = esrc[e], r1 = esrc[e + 8];
    uint4 v0 = hp[(size_t)r0 * 8 + fq];
    uint4 v1 = hp[(size_t)r1 * 8 + fq];
    float d0 = 1.f, d1 = 1.f;
    if (SCALE_SRC) { d0 = dinv[r0]; d1 = dinv[r1]; }
    acc[0] += bflo(v0.x) * d0; acc[1] += bfhi(v0.x) * d0;
    acc[2] += bflo(v0.y) * d0; acc[3] += bfhi(v0.y) * d0;
    acc[4] += bflo(v0.z) * d0; acc[5] += bfhi(v0.z) * d0;
    acc[6] += bflo(v0.w) * d0; acc[7] += bfhi(v0.w) * d0;
    acc[0] += bflo(v1.x) * d1; acc[1] += bfhi(v1.x) * d1;
    acc[2] += bflo(v1.y) * d1; acc[3] += bfhi(v1.y) * d1;
    acc[4] += bflo(v1.z) * d1; acc[5] += bfhi(v1.z) * d1;
    acc[6] += bflo(v1.w) * d1; acc[7] += bfhi(v1.w) * d1;
  }
  if (e < s1) {
    int r = esrc[e];
    uint4 v = hp[(size_t)r * 8 + fq];
    float d = SCALE_SRC ? dinv[r] : 1.f;
    acc[0] += bflo(v.x) * d; acc[1] += bfhi(v.x) * d;
    acc[2] += bflo(v.y) * d; acc[3] += bfhi(v.y) * d;
    acc[4] += bflo(v.z) * d; acc[5] += bfhi(v.z) * d;
    acc[6] += bflo(v.w) * d; acc[7] += bfhi(v.w) * d;
  }
#pragma unroll
  for (int off = 8; off < 64; off <<= 1) {
#pragma unroll
    for (int i = 0; i < 8; ++i) acc[i] += __shfl_xor(acc[i], off);
  }
  if (qid == 0) {
    float dn = dinv[n];
    uint4 sv = hp[(size_t)n * 8 + fq];
    float sc = SCALE_SRC ? dn : 1.f;
    float r[8];
    r[0] = (acc[0] + bflo(sv.x) * sc) * dn; r[1] = (acc[1] + bfhi(sv.x) * sc) * dn;
    r[2] = (acc[2] + bflo(sv.y) * sc) * dn; r[3] = (acc[3] + bfhi(sv.y) * sc) * dn;
    r[4] = (acc[4] + bflo(sv.z) * sc) * dn; r[5] = (acc[5] + bfhi(sv.z) * sc) * dn;
    r[6] = (acc[6] + bflo(sv.w) * sc) * dn; r[7] = (acc[7] + bfhi(sv.w) * sc) * dn;
    if (BIAS) {
      const float4* b4p = (const float4*)bias;
      float4 bA = b4p[fq * 2], bB = b4p[fq * 2 + 1];
      r[0] += bA.x; r[1] += bA.y; r[2] += bA.z; r[3] += bA.w;
      r[4] += bB.x; r[5] += bB.y; r[6] += bB.z; r[7] += bB.w;
    }
    if (RELU) {
#pragma unroll
      for (int i = 0; i < 8; ++i) r[i] = fmaxf(r[i], 0.f);
    }
    uint4 o;
    o.x = pack2(r[0], r[1]); o.y = pack2(r[2], r[3]);
    o.z = pack2(r[4], r[5]); o.w = pack2(r[6], r[7]);
    out[(size_t)n * 8 + fq] = o;
  }
}

// per-graph segmented sum over sorted batch
__global__ void k_pool(const ushort* __restrict__ agg4, const int* __restrict__ gstart,
                       float* __restrict__ P) {
  __shared__ float part[4][GH];
  int g = blockIdx.x;
  int f = threadIdx.x & 63, r = threadIdx.x >> 6;
  int a = gstart[g], b = gstart[g + 1];
  float acc = 0.f;
  for (int n = a + r; n < b; n += 4)
    acc += __uint_as_float(((uint32_t)agg4[(size_t)n * GH + f]) << 16);
  part[r][f] = acc;
  __syncthreads();
  if (r == 0) P[(size_t)g * GH + f] = part[0][f] + part[1][f] + part[2][f] + part[3][f];
}

__global__ void k_head(const float* __restrict__ P, const int* __restrict__ gstart,
                       const float* __restrict__ W4, const float* __restrict__ b4,
                       float* __restrict__ out) {
  int g = blockIdx.x;
  int lane = threadIdx.x;  // 64
  float c = fmaxf((float)(gstart[g + 1] - gstart[g]), 1.0f);
  float p = P[(size_t)g * GH + lane] / c;
  float t[GOUT];
#pragma unroll
  for (int j = 0; j < GOUT; ++j) {
    float r = p * W4[lane * GOUT + j];
#pragma unroll
    for (int off = 1; off < 64; off <<= 1) r += __shfl_xor(r, off);
    t[j] = r + b4[j];
  }
  if (lane == 0) {
    float mx = -1e30f;
#pragma unroll
    for (int j = 0; j < GOUT; ++j) mx = fmaxf(mx, t[j]);
    float sum = 0.f;
#pragma unroll
    for (int j = 0; j < GOUT; ++j) sum += expf(t[j] - mx);
    float lse = mx + logf(sum);
#pragma unroll
    for (int j = 0; j < GOUT; ++j) out[(size_t)g * GOUT + j] = t[j] - lse;
  }
}

static inline int cdiv(long a, long b) { return (int)((a + b - 1) / b); }

extern "C" void kernel_launch(void* const* d_in, const int* in_sizes, int n_in,
                              void* d_out, int out_size, void* d_ws, size_t ws_size,
                              hipStream_t stream) {
  const float* x  = (const float*)d_in[0];
  const int*   ei = (const int*)d_in[1];
  const int*   bt = (const int*)d_in[2];
  const float* W1 = (const float*)d_in[3];
  const float* b1 = (const float*)d_in[4];
  const float* W2 = (const float*)d_in[5];
  const float* b2 = (const float*)d_in[6];
  const float* W3 = (const float*)d_in[7];
  const float* b3 = (const float*)d_in[8];
  const float* W4 = (const float*)d_in[9];
  const float* b4 = (const float*)d_in[10];
  float* out = (float*)d_out;

  ushort* HP   = (ushort*)d_ws;                       // NN*64 bf16
  ushort* ACT  = HP + (size_t)NN * GH;                // NN*64 bf16
  float* dinv  = (float*)(ACT + (size_t)NN * GH);     // NN
  float* P     = dinv + NN;                           // NG*64
  int* gstart  = (int*)(P + (size_t)NG * GH);         // NG+1
  int* deg     = gstart + NG + 3;                     // NN
  int* pref    = deg + NN;                            // NN
  int* rowptr  = pref + NN;                           // NN+1
  int* cursor  = rowptr + NN + 1;                     // NN
  int* bsum    = cursor + NN;                         // NB
  int* esrc    = bsum + ((NB + 3) & ~3);              // NE

  const int* row = ei;        // edge_index[0] = source
  const int* col = ei + NE;   // edge_index[1] = target (aggregate here)

  // --- CSR build + dinv + graph starts ---
  k_zero_i<<<cdiv(NN, TPB), TPB, 0, stream>>>(deg, NN);
  k_hist<<<cdiv(NE, TPB), TPB, 0, stream>>>(col, deg);
  k_dinv<<<cdiv(NN, TPB), TPB, 0, stream>>>(deg, dinv);
  k_gstart<<<cdiv(NG + 1, TPB), TPB, 0, stream>>>(bt, gstart);
  k_scan1<<<NB, TPB, 0, stream>>>(deg, pref, bsum);
  k_scan2<<<1, TPB, 0, stream>>>(bsum);
  k_scan3<<<cdiv(NN + 1, TPB), TPB, 0, stream>>>(pref, bsum, rowptr, cursor);
  k_scatter<<<cdiv(NE, TPB), TPB, 0, stream>>>(row, col, cursor, esrc);

  const int gridN = cdiv(NN, TPB / 64);

  // --- layer 1 ---
  k_mm_f32<<<MMBLK, TPB, 0, stream>>>(x, W1, dinv, HP);
  k_agg<true, false, true><<<gridN, TPB, 0, stream>>>(rowptr, esrc, dinv, (const uint4*)HP, b1, (uint4*)ACT);
  // --- layer 2 ---
  k_mm_bf<<<MMBLK, TPB, 0, stream>>>(ACT, W2, dinv, HP);
  k_agg<true, false, true><<<gridN, TPB, 0, stream>>>(rowptr, esrc, dinv, (const uint4*)HP, b2, (uint4*)ACT);
  // --- layer 3 ---
  k_mm_bf<<<MMBLK, TPB, 0, stream>>>(ACT, W3, dinv, HP);
  k_agg<true, false, true><<<gridN, TPB, 0, stream>>>(rowptr, esrc, dinv, (const uint4*)HP, b3, (uint4*)ACT);
  // --- layer 4 (algebraic swap): AGG4 = Â·H3 into HP, no bias/relu ---
  k_agg<false, true, false><<<gridN, TPB, 0, stream>>>(rowptr, esrc, dinv, (const uint4*)ACT, nullptr, (uint4*)HP);

  // --- pool + head ---
  k_pool<<<NG, TPB, 0, stream>>>(HP, gstart, P);
  k_head<<<NG, 64, 0, stream>>>(P, gstart, W4, b4, out);
}

// Round 6
// 443.222 us; speedup vs baseline: 3.8176x; 1.3604x over previous
//
#include <hip/hip_runtime.h>
#include <math.h>
#include <stdint.h>

#define NN 100000
#define NE 1600000
#define GIN 128
#define GH 64
#define GOUT 10
#define NG 512
#define TPB 256
#define SCB 1024
#define NB ((NN + SCB - 1) / SCB)   // 98 scan blocks
#define MMBLK 512                   // blocks for MFMA matmuls (2048 waves)

typedef __attribute__((ext_vector_type(8))) short bf16x8;
typedef __attribute__((ext_vector_type(4))) float f32x4;

// ---- bf16 helpers (RNE pack) ----
__device__ __forceinline__ float bflo(uint32_t u) { return __uint_as_float(u << 16); }
__device__ __forceinline__ float bfhi(uint32_t u) { return __uint_as_float(u & 0xFFFF0000u); }
__device__ __forceinline__ uint32_t f2bf(float f) {
  uint32_t b = __float_as_uint(f);
  return (b + 0x7FFFu + ((b >> 16) & 1u)) >> 16;
}
__device__ __forceinline__ uint32_t pack2(float lo, float hi) { return f2bf(lo) | (f2bf(hi) << 16); }
__device__ __forceinline__ short bfs(float f) { return (short)f2bf(f); }

__global__ void k_zero_i(int* __restrict__ p, int n) {
  int i = blockIdx.x * TPB + threadIdx.x;
  if (i < n) p[i] = 0;
}

__global__ void k_hist(const int* __restrict__ col, int* __restrict__ deg) {
  int e = blockIdx.x * TPB + threadIdx.x;
  if (e < NE) atomicAdd(&deg[col[e]], 1);
}

__global__ void k_dinv(const int* __restrict__ deg, float* __restrict__ dinv) {
  int i = blockIdx.x * TPB + threadIdx.x;
  if (i < NN) dinv[i] = rsqrtf((float)deg[i] + 1.0f);  // +1 self-loop
}

// gstart[g] = first node index with batch >= g (batch sorted); gstart[NG] = NN
__global__ void k_gstart(const int* __restrict__ batch, int* __restrict__ gstart) {
  int g = blockIdx.x * TPB + threadIdx.x;
  if (g > NG) return;
  int lo = 0, hi = NN;
  while (lo < hi) { int mid = (lo + hi) >> 1; if (batch[mid] < g) lo = mid + 1; else hi = mid; }
  gstart[g] = lo;
}

__global__ void k_scan1(const int* __restrict__ deg, int* __restrict__ pref,
                        int* __restrict__ bsum) {
  __shared__ int wsum[8];
  int t = threadIdx.x;
  int base = blockIdx.x * SCB;
  int v[4]; int s = 0;
#pragma unroll
  for (int j = 0; j < 4; ++j) {
    int idx = base + t * 4 + j;
    v[j] = (idx < NN) ? deg[idx] : 0;
    s += v[j];
  }
  int lane = t & 63, wid = t >> 6;
  int sc = s;
#pragma unroll
  for (int off = 1; off < 64; off <<= 1) {
    int u = __shfl_up(sc, off);
    if (lane >= off) sc += u;
  }
  if (lane == 63) wsum[wid] = sc;
  __syncthreads();
  if (t == 0) {
    int a = 0;
    for (int w = 0; w < 4; ++w) { int x = wsum[w]; wsum[w] = a; a += x; }
  }
  __syncthreads();
  int excl = sc - s + wsum[wid];
#pragma unroll
  for (int j = 0; j < 4; ++j) {
    int idx = base + t * 4 + j;
    if (idx < NN) pref[idx] = excl;
    excl += v[j];
  }
  if (t == TPB - 1) bsum[blockIdx.x] = excl;  // block total
}

__global__ void k_scan2(int* __restrict__ bsum) {
  __shared__ int l[NB];
  int t = threadIdx.x;
  if (t < NB) l[t] = bsum[t];
  __syncthreads();
  if (t == 0) {
    int a = 0;
    for (int i = 0; i < NB; ++i) { int x = l[i]; l[i] = a; a += x; }
  }
  __syncthreads();
  if (t < NB) bsum[t] = l[t];
}

__global__ void k_scan3(const int* __restrict__ pref, const int* __restrict__ bsum,
                        int* __restrict__ rowptr, int* __restrict__ cursor) {
  int i = blockIdx.x * TPB + threadIdx.x;
  if (i < NN) {
    int v = pref[i] + bsum[i / SCB];
    rowptr[i] = v;
    cursor[i] = v;
  }
  if (i == NN) rowptr[NN] = NE;
}

__global__ void k_scatter(const int* __restrict__ row, const int* __restrict__ col,
                          int* __restrict__ cursor, int* __restrict__ esrc) {
  int e = blockIdx.x * TPB + threadIdx.x;
  if (e < NE) {
    int c = col[e];
    int p = atomicAdd(&cursor[c], 1);
    esrc[p] = row[e];
  }
}

// ---- MFMA matmul, layer 1: X f32 [NN,128] @ W[128,64] -> bf16 Y, *dinv ----
// Per wave: 16-row tile. A-frag = direct 32B row segment (f32->bf16). B-frags
// (W) in registers, loaded once. C/D: col=lane&15, row=(lane>>4)*4+reg (m89).
__global__ __launch_bounds__(TPB, 1)
void k_mm1(const float* __restrict__ X, const float* __restrict__ W,
           const float* __restrict__ dinv, ushort* __restrict__ Y) {
  int lane = threadIdx.x & 63;
  int wv = blockIdx.x * (TPB / 64) + (threadIdx.x >> 6);
  const int nwv = MMBLK * (TPB / 64);
  int kb = (lane >> 4) * 8;   // k-base within a 32-k tile
  int fcol = lane & 15;       // B col / C col / A row index
  bf16x8 bfr[4][4];
#pragma unroll
  for (int kt = 0; kt < 4; ++kt)
#pragma unroll
    for (int ct = 0; ct < 4; ++ct)
#pragma unroll
      for (int j = 0; j < 8; ++j)
        bfr[kt][ct][j] = bfs(W[(size_t)(kt * 32 + kb + j) * GH + ct * 16 + fcol]);
  const int NT = NN / 16;  // 6250
  for (int t = wv; t < NT; t += nwv) {
    int n0 = t * 16;
    const float* xr = X + (size_t)(n0 + fcol) * GIN;
    f32x4 acc[4] = {{0,0,0,0},{0,0,0,0},{0,0,0,0},{0,0,0,0}};
#pragma unroll
    for (int kt = 0; kt < 4; ++kt) {
      float4 p = *(const float4*)(xr + kt * 32 + kb);
      float4 q = *(const float4*)(xr + kt * 32 + kb + 4);
      bf16x8 a;
      a[0] = bfs(p.x); a[1] = bfs(p.y); a[2] = bfs(p.z); a[3] = bfs(p.w);
      a[4] = bfs(q.x); a[5] = bfs(q.y); a[6] = bfs(q.z); a[7] = bfs(q.w);
#pragma unroll
      for (int ct = 0; ct < 4; ++ct)
        acc[ct] = __builtin_amdgcn_mfma_f32_16x16x32_bf16(a, bfr[kt][ct], acc[ct], 0, 0, 0);
    }
    int rbase = (lane >> 4) * 4;
#pragma unroll
    for (int reg = 0; reg < 4; ++reg) {
      int n = n0 + rbase + reg;
      float d = dinv[n];
#pragma unroll
      for (int ct = 0; ct < 4; ++ct)
        Y[(size_t)n * GH + ct * 16 + fcol] = (ushort)f2bf(acc[ct][reg] * d);
    }
  }
}

// ---- MFMA matmul, layers 2/3: X bf16 [NN,64] @ W[64,64] -> bf16 Y, *dinv ----
__global__ __launch_bounds__(TPB, 1)
void k_mmh(const ushort* __restrict__ X, const float* __restrict__ W,
           const float* __restrict__ dinv, ushort* __restrict__ Y) {
  int lane = threadIdx.x & 63;
  int wv = blockIdx.x * (TPB / 64) + (threadIdx.x >> 6);
  const int nwv = MMBLK * (TPB / 64);
  int kb = (lane >> 4) * 8;
  int fcol = lane & 15;
  bf16x8 bfr[2][4];
#pragma unroll
  for (int kt = 0; kt < 2; ++kt)
#pragma unroll
    for (int ct = 0; ct < 4; ++ct)
#pragma unroll
      for (int j = 0; j < 8; ++j)
        bfr[kt][ct][j] = bfs(W[(size_t)(kt * 32 + kb + j) * GH + ct * 16 + fcol]);
  const int NT = NN / 16;
  for (int t = wv; t < NT; t += nwv) {
    int n0 = t * 16;
    const ushort* xr = X + (size_t)(n0 + fcol) * GH;
    f32x4 acc[4] = {{0,0,0,0},{0,0,0,0},{0,0,0,0},{0,0,0,0}};
#pragma unroll
    for (int kt = 0; kt < 2; ++kt) {
      bf16x8 a = *(const bf16x8*)(xr + kt * 32 + kb);
#pragma unroll
      for (int ct = 0; ct < 4; ++ct)
        acc[ct] = __builtin_amdgcn_mfma_f32_16x16x32_bf16(a, bfr[kt][ct], acc[ct], 0, 0, 0);
    }
    int rbase = (lane >> 4) * 4;
#pragma unroll
    for (int reg = 0; reg < 4; ++reg) {
      int n = n0 + rbase + reg;
      float d = dinv[n];
#pragma unroll
      for (int ct = 0; ct < 4; ++ct)
        Y[(size_t)n * GH + ct * 16 + fcol] = (ushort)f2bf(acc[ct][reg] * d);
    }
  }
}

// One wave per node; 8 groups of 8 lanes; group q handles edges s0+q, s0+q+8, ...
// Each lane loads uint4 = 8 bf16 feats. acc f32; cross-group shfl reduction.
template<bool RELU, bool SCALE_SRC, bool BIAS>
__global__ void k_agg(const int* __restrict__ rowptr, const int* __restrict__ esrc,
                      const float* __restrict__ dinv, const uint4* __restrict__ hp,
                      const float* __restrict__ bias, uint4* __restrict__ out) {
  int n = blockIdx.x * (TPB / 64) + (threadIdx.x >> 6);
  if (n >= NN) return;
  int lane = threadIdx.x & 63;
  int qid = lane >> 3, fq = lane & 7;
  int s0 = rowptr[n], s1 = rowptr[n + 1];
  float acc[8] = {0.f, 0.f, 0.f, 0.f, 0.f, 0.f, 0.f, 0.f};
  int e = s0 + qid;
  for (; e + 8 < s1; e += 16) {
    int r0 = esrc[e], r1 = esrc[e + 8];
    uint4 v0 = hp[(size_t)r0 * 8 + fq];
    uint4 v1 = hp[(size_t)r1 * 8 + fq];
    float d0 = 1.f, d1 = 1.f;
    if (SCALE_SRC) { d0 = dinv[r0]; d1 = dinv[r1]; }
    acc[0] += bflo(v0.x) * d0; acc[1] += bfhi(v0.x) * d0;
    acc[2] += bflo(v0.y) * d0; acc[3] += bfhi(v0.y) * d0;
    acc[4] += bflo(v0.z) * d0; acc[5] += bfhi(v0.z) * d0;
    acc[6] += bflo(v0.w) * d0; acc[7] += bfhi(v0.w) * d0;
    acc[0] += bflo(v1.x) * d1; acc[1] += bfhi(v1.x) * d1;
    acc[2] += bflo(v1.y) * d1; acc[3] += bfhi(v1.y) * d1;
    acc[4] += bflo(v1.z) * d1; acc[5] += bfhi(v1.z) * d1;
    acc[6] += bflo(v1.w) * d1; acc[7] += bfhi(v1.w) * d1;
  }
  if (e < s1) {
    int r = esrc[e];
    uint4 v = hp[(size_t)r * 8 + fq];
    float d = SCALE_SRC ? dinv[r] : 1.f;
    acc[0] += bflo(v.x) * d; acc[1] += bfhi(v.x) * d;
    acc[2] += bflo(v.y) * d; acc[3] += bfhi(v.y) * d;
    acc[4] += bflo(v.z) * d; acc[5] += bfhi(v.z) * d;
    acc[6] += bflo(v.w) * d; acc[7] += bfhi(v.w) * d;
  }
#pragma unroll
  for (int off = 8; off < 64; off <<= 1) {
#pragma unroll
    for (int i = 0; i < 8; ++i) acc[i] += __shfl_xor(acc[i], off);
  }
  if (qid == 0) {
    float dn = dinv[n];
    uint4 sv = hp[(size_t)n * 8 + fq];
    float sc = SCALE_SRC ? dn : 1.f;
    float r[8];
    r[0] = (acc[0] + bflo(sv.x) * sc) * dn; r[1] = (acc[1] + bfhi(sv.x) * sc) * dn;
    r[2] = (acc[2] + bflo(sv.y) * sc) * dn; r[3] = (acc[3] + bfhi(sv.y) * sc) * dn;
    r[4] = (acc[4] + bflo(sv.z) * sc) * dn; r[5] = (acc[5] + bfhi(sv.z) * sc) * dn;
    r[6] = (acc[6] + bflo(sv.w) * sc) * dn; r[7] = (acc[7] + bfhi(sv.w) * sc) * dn;
    if (BIAS) {
      const float4* b4p = (const float4*)bias;
      float4 bA = b4p[fq * 2], bB = b4p[fq * 2 + 1];
      r[0] += bA.x; r[1] += bA.y; r[2] += bA.z; r[3] += bA.w;
      r[4] += bB.x; r[5] += bB.y; r[6] += bB.z; r[7] += bB.w;
    }
    if (RELU) {
#pragma unroll
      for (int i = 0; i < 8; ++i) r[i] = fmaxf(r[i], 0.f);
    }
    uint4 o;
    o.x = pack2(r[0], r[1]); o.y = pack2(r[2], r[3]);
    o.z = pack2(r[4], r[5]); o.w = pack2(r[6], r[7]);
    out[(size_t)n * 8 + fq] = o;
  }
}

// per-graph segmented sum over sorted batch
__global__ void k_pool(const ushort* __restrict__ agg4, const int* __restrict__ gstart,
                       float* __restrict__ P) {
  __shared__ float part[4][GH];
  int g = blockIdx.x;
  int f = threadIdx.x & 63, r = threadIdx.x >> 6;
  int a = gstart[g], b = gstart[g + 1];
  float acc = 0.f;
  for (int n = a + r; n < b; n += 4)
    acc += __uint_as_float(((uint32_t)agg4[(size_t)n * GH + f]) << 16);
  part[r][f] = acc;
  __syncthreads();
  if (r == 0) P[(size_t)g * GH + f] = part[0][f] + part[1][f] + part[2][f] + part[3][f];
}

__global__ void k_head(const float* __restrict__ P, const int* __restrict__ gstart,
                       const float* __restrict__ W4, const float* __restrict__ b4,
                       float* __restrict__ out) {
  int g = blockIdx.x;
  int lane = threadIdx.x;  // 64
  float c = fmaxf((float)(gstart[g + 1] - gstart[g]), 1.0f);
  float p = P[(size_t)g * GH + lane] / c;
  float t[GOUT];
#pragma unroll
  for (int j = 0; j < GOUT; ++j) {
    float r = p * W4[lane * GOUT + j];
#pragma unroll
    for (int off = 1; off < 64; off <<= 1) r += __shfl_xor(r, off);
    t[j] = r + b4[j];
  }
  if (lane == 0) {
    float mx = -1e30f;
#pragma unroll
    for (int j = 0; j < GOUT; ++j) mx = fmaxf(mx, t[j]);
    float sum = 0.f;
#pragma unroll
    for (int j = 0; j < GOUT; ++j) sum += expf(t[j] - mx);
    float lse = mx + logf(sum);
#pragma unroll
    for (int j = 0; j < GOUT; ++j) out[(size_t)g * GOUT + j] = t[j] - lse;
  }
}

static inline int cdiv(long a, long b) { return (int)((a + b - 1) / b); }

extern "C" void kernel_launch(void* const* d_in, const int* in_sizes, int n_in,
                              void* d_out, int out_size, void* d_ws, size_t ws_size,
                              hipStream_t stream) {
  const float* x  = (const float*)d_in[0];
  const int*   ei = (const int*)d_in[1];
  const int*   bt = (const int*)d_in[2];
  const float* W1 = (const float*)d_in[3];
  const float* b1 = (const float*)d_in[4];
  const float* W2 = (const float*)d_in[5];
  const float* b2 = (const float*)d_in[6];
  const float* W3 = (const float*)d_in[7];
  const float* b3 = (const float*)d_in[8];
  const float* W4 = (const float*)d_in[9];
  const float* b4 = (const float*)d_in[10];
  float* out = (float*)d_out;

  ushort* HP   = (ushort*)d_ws;                       // NN*64 bf16
  ushort* ACT  = HP + (size_t)NN * GH;                // NN*64 bf16
  float* dinv  = (float*)(ACT + (size_t)NN * GH);     // NN
  float* P     = dinv + NN;                           // NG*64
  int* gstart  = (int*)(P + (size_t)NG * GH);         // NG+1
  int* deg     = gstart + NG + 3;                     // NN
  int* pref    = deg + NN;                            // NN
  int* rowptr  = pref + NN;                           // NN+1
  int* cursor  = rowptr + NN + 1;                     // NN
  int* bsum    = cursor + NN;                         // NB
  int* esrc    = bsum + ((NB + 3) & ~3);              // NE

  const int* row = ei;        // edge_index[0] = source
  const int* col = ei + NE;   // edge_index[1] = target (aggregate here)

  // --- CSR build + dinv + graph starts ---
  k_zero_i<<<cdiv(NN, TPB), TPB, 0, stream>>>(deg, NN);
  k_hist<<<cdiv(NE, TPB), TPB, 0, stream>>>(col, deg);
  k_dinv<<<cdiv(NN, TPB), TPB, 0, stream>>>(deg, dinv);
  k_gstart<<<cdiv(NG + 1, TPB), TPB, 0, stream>>>(bt, gstart);
  k_scan1<<<NB, TPB, 0, stream>>>(deg, pref, bsum);
  k_scan2<<<1, TPB, 0, stream>>>(bsum);
  k_scan3<<<cdiv(NN + 1, TPB), TPB, 0, stream>>>(pref, bsum, rowptr, cursor);
  k_scatter<<<cdiv(NE, TPB), TPB, 0, stream>>>(row, col, cursor, esrc);

  const int gridN = cdiv(NN, TPB / 64);

  // --- layer 1 ---
  k_mm1<<<MMBLK, TPB, 0, stream>>>(x, W1, dinv, HP);
  k_agg<true, false, true><<<gridN, TPB, 0, stream>>>(rowptr, esrc, dinv, (const uint4*)HP, b1, (uint4*)ACT);
  // --- layer 2 ---
  k_mmh<<<MMBLK, TPB, 0, stream>>>(ACT, W2, dinv, HP);
  k_agg<true, false, true><<<gridN, TPB, 0, stream>>>(rowptr, esrc, dinv, (const uint4*)HP, b2, (uint4*)ACT);
  // --- layer 3 ---
  k_mmh<<<MMBLK, TPB, 0, stream>>>(ACT, W3, dinv, HP);
  k_agg<true, false, true><<<gridN, TPB, 0, stream>>>(rowptr, esrc, dinv, (const uint4*)HP, b3, (uint4*)ACT);
  // --- layer 4 (algebraic swap): AGG4 = Â·H3 into HP, no bias/relu ---
  k_agg<false, true, false><<<gridN, TPB, 0, stream>>>(rowptr, esrc, dinv, (const uint4*)ACT, nullptr, (uint4*)HP);

  // --- pool + head ---
  k_pool<<<NG, TPB, 0, stream>>>(HP, gstart, P);
  k_head<<<NG, 64, 0, stream>>>(P, gstart, W4, b4, out);
}